// Round 1
// baseline (11069.534 us; speedup 1.0000x reference)
//
#include <hip/hip_runtime.h>
#include <hip/hip_bf16.h>
#include <math.h>

// SpatialTemporalModel: GCN(2-layer, symmetric-norm w/ self loops) x24 steps
// -> LSTM(LH=128) -> MLP head. Round 1: all-fp32 correctness-first build.
//
// agg(xw)[v] = dinv[v] * ( sum_{src->v} dinv[src]*xw[src] + dinv[v]*xw[v] )
// so with xw' = dinv .* xw :  agg = dinv[v] * ( csr_sum(xw') + xw'[v] )

#define RB 64  // rows per LSTM block

__device__ __forceinline__ float sigf(float x) { return 1.f / (1.f + __expf(-x)); }
__device__ __forceinline__ float tanhfast(float x) { return 1.f - 2.f / (1.f + __expf(2.f * x)); }
__device__ __forceinline__ float dot4(float4 a, float4 b, float acc) {
    return fmaf(a.x, b.x, fmaf(a.y, b.y, fmaf(a.z, b.z, fmaf(a.w, b.w, acc))));
}

// ---------------- CSR build ----------------
__global__ void k_count(const int* __restrict__ dst, int E, int* __restrict__ deg) {
    int e = blockIdx.x * blockDim.x + threadIdx.x;
    if (e < E) atomicAdd(&deg[dst[e]], 1);
}

__global__ void k_dinv(const int* __restrict__ deg, float* __restrict__ dinv, int N) {
    int v = blockIdx.x * blockDim.x + threadIdx.x;
    if (v < N) dinv[v] = rsqrtf((float)deg[v] + 1.0f);
}

__global__ __launch_bounds__(1024) void k_scan(const int* __restrict__ deg, int* __restrict__ row_ptr,
                                               int* __restrict__ cursor, int N) {
    __shared__ int part[1024];
    int tid = threadIdx.x;
    int C = (N + 1023) >> 10;
    int s0 = tid * C;
    int s1 = min(s0 + C, N);
    int s = 0;
    for (int i = s0; i < s1; ++i) s += deg[i];
    part[tid] = s;
    __syncthreads();
    for (int off = 1; off < 1024; off <<= 1) {
        int v = (tid >= off) ? part[tid - off] : 0;
        __syncthreads();
        part[tid] += v;
        __syncthreads();
    }
    int base = (tid == 0) ? 0 : part[tid - 1];
    for (int i = s0; i < s1; ++i) {
        row_ptr[i] = base;
        cursor[i] = base;
        base += deg[i];
    }
    if (tid == 1023) row_ptr[N] = base;
}

__global__ void k_fill(const int* __restrict__ src, const int* __restrict__ dst, int E,
                       int* __restrict__ cursor, int* __restrict__ col) {
    int e = blockIdx.x * blockDim.x + threadIdx.x;
    if (e < E) {
        int d = dst[e];
        int p = atomicAdd(&cursor[d], 1);
        col[p] = src[e];
    }
}

// ---------------- GCN: x_t @ W1, pre-scaled by dinv ----------------
// block 256 = 4 waves; wave rg owns rows v0..v0+3; lane = output channel h.
__global__ __launch_bounds__(256) void k_gemm_xW1(const float* __restrict__ x, const float* __restrict__ W1,
                                                  const float* __restrict__ dinv, float* __restrict__ out, int N) {
    __shared__ float w[16 * 64];
    int tid = threadIdx.x;
    ((float4*)w)[tid] = ((const float4*)W1)[tid];  // 1024 floats = 256 f4
    __syncthreads();
    int h = tid & 63;
    int rg = __builtin_amdgcn_readfirstlane(tid >> 6);
    int v0 = blockIdx.x * 16 + rg * 4;
    float acc[4] = {0.f, 0.f, 0.f, 0.f};
#pragma unroll
    for (int r = 0; r < 4; ++r) {
        if (v0 + r < N) {
            const float4* xr = (const float4*)(x + (size_t)(v0 + r) * 16);
            float4 xa = xr[0], xb = xr[1], xc = xr[2], xd = xr[3];
            float a = acc[r];
            a = fmaf(xa.x, w[0 * 64 + h], a);  a = fmaf(xa.y, w[1 * 64 + h], a);
            a = fmaf(xa.z, w[2 * 64 + h], a);  a = fmaf(xa.w, w[3 * 64 + h], a);
            a = fmaf(xb.x, w[4 * 64 + h], a);  a = fmaf(xb.y, w[5 * 64 + h], a);
            a = fmaf(xb.z, w[6 * 64 + h], a);  a = fmaf(xb.w, w[7 * 64 + h], a);
            a = fmaf(xc.x, w[8 * 64 + h], a);  a = fmaf(xc.y, w[9 * 64 + h], a);
            a = fmaf(xc.z, w[10 * 64 + h], a); a = fmaf(xc.w, w[11 * 64 + h], a);
            a = fmaf(xd.x, w[12 * 64 + h], a); a = fmaf(xd.y, w[13 * 64 + h], a);
            a = fmaf(xd.z, w[14 * 64 + h], a); a = fmaf(xd.w, w[15 * 64 + h], a);
            acc[r] = a;
        }
    }
#pragma unroll
    for (int r = 0; r < 4; ++r)
        if (v0 + r < N) out[(size_t)(v0 + r) * 64 + h] = acc[r] * dinv[v0 + r];
}

// ---------------- GCN: h1 @ W2, pre-scaled by dinv ----------------
__global__ __launch_bounds__(256) void k_gemm_hW2(const float* __restrict__ hin, const float* __restrict__ W2,
                                                  const float* __restrict__ dinv, float* __restrict__ out, int N) {
    __shared__ float w[64 * 64];
    int tid = threadIdx.x;
#pragma unroll
    for (int i = 0; i < 4; ++i) ((float4*)w)[tid + 256 * i] = ((const float4*)W2)[tid + 256 * i];
    __syncthreads();
    int h = tid & 63;
    int rg = __builtin_amdgcn_readfirstlane(tid >> 6);
    int v0 = blockIdx.x * 16 + rg * 4;
    float acc[4] = {0.f, 0.f, 0.f, 0.f};
#pragma unroll 4
    for (int k4 = 0; k4 < 16; ++k4) {
        float w0 = w[(4 * k4 + 0) * 64 + h];
        float w1 = w[(4 * k4 + 1) * 64 + h];
        float w2v = w[(4 * k4 + 2) * 64 + h];
        float w3 = w[(4 * k4 + 3) * 64 + h];
#pragma unroll
        for (int r = 0; r < 4; ++r) {
            if (v0 + r < N) {
                float4 xv = *(const float4*)(hin + (size_t)(v0 + r) * 64 + 4 * k4);
                float a = acc[r];
                a = fmaf(xv.x, w0, a);
                a = fmaf(xv.y, w1, a);
                a = fmaf(xv.z, w2v, a);
                a = fmaf(xv.w, w3, a);
                acc[r] = a;
            }
        }
    }
#pragma unroll
    for (int r = 0; r < 4; ++r)
        if (v0 + r < N) out[(size_t)(v0 + r) * 64 + h] = acc[r] * dinv[v0 + r];
}

// ---------------- aggregation: relu(dinv[v]*(self + csr_sum) + bias) ----------------
// wave per node, lane = channel. Gathers are 256B/row coalesced out of L2/L3.
__global__ __launch_bounds__(256) void k_agg(const float* __restrict__ tin, const float* __restrict__ dinv,
                                             const int* __restrict__ row_ptr, const int* __restrict__ col,
                                             const float* __restrict__ bias, float* __restrict__ out, int N) {
    int lane = threadIdx.x & 63;
    int v = blockIdx.x * 4 + (threadIdx.x >> 6);
    v = __builtin_amdgcn_readfirstlane(v);
    if (v >= N) return;
    float s = tin[(size_t)v * 64 + lane];
    int b = row_ptr[v];
    int e = row_ptr[v + 1];
    for (int i = b; i < e; ++i) {
        int c = col[i];
        s += tin[(size_t)c * 64 + lane];
    }
    float r = fmaf(dinv[v], s, bias[lane]);
    out[(size_t)v * 64 + lane] = fmaxf(r, 0.f);
}

// ---------------- fused LSTM step: g = [x|h] @ Wcat^T + b ; gate; update h,c in place ----------------
// block 512 threads: j = tid&127 (channel, owns all 4 gate cols -> gating is thread-local);
// rg = tid>>7 picks 16 of the block's 64 rows. x|h staged in LDS (49KB), broadcast reads.
__global__ __launch_bounds__(512) void k_lstm(const float* __restrict__ xin, float* __restrict__ hbuf,
                                              float* __restrict__ cbuf, const float* __restrict__ W_ih,
                                              const float* __restrict__ W_hh, const float* __restrict__ b_ih,
                                              const float* __restrict__ b_hh, int N) {
    __shared__ float xs[RB][192];
    int tid = threadIdx.x;
    int row0 = blockIdx.x * RB;
    // stage x (64 cols/row) and h_prev (128 cols/row)
    for (int idx = tid; idx < RB * 16; idx += 512) {
        int r = idx >> 4, c = idx & 15;
        float4 v4 = make_float4(0.f, 0.f, 0.f, 0.f);
        if (row0 + r < N) v4 = ((const float4*)xin)[(size_t)(row0 + r) * 16 + c];
        *(float4*)&xs[r][c * 4] = v4;
    }
    for (int idx = tid; idx < RB * 32; idx += 512) {
        int r = idx >> 5, c = idx & 31;
        float4 v4 = make_float4(0.f, 0.f, 0.f, 0.f);
        if (row0 + r < N) v4 = ((const float4*)hbuf)[(size_t)(row0 + r) * 32 + c];
        *(float4*)&xs[r][64 + c * 4] = v4;
    }
    __syncthreads();

    int j = tid & 127;
    int rg = tid >> 7;
    int lr0 = rg * 16;
    float bi = b_ih[j] + b_hh[j];
    float bf = b_ih[128 + j] + b_hh[128 + j];
    float bg = b_ih[256 + j] + b_hh[256 + j];
    float bo = b_ih[384 + j] + b_hh[384 + j];
    float ai[16], af[16], ag[16], ao[16];
#pragma unroll
    for (int r = 0; r < 16; ++r) { ai[r] = bi; af[r] = bf; ag[r] = bg; ao[r] = bo; }

    // phase 1: K = 0..63 (input projection, W_ih is (512,64) row-major)
    const float4* wip = (const float4*)(W_ih + (size_t)j * 64);
    const float4* wfp = (const float4*)(W_ih + (size_t)(128 + j) * 64);
    const float4* wgp = (const float4*)(W_ih + (size_t)(256 + j) * 64);
    const float4* wop = (const float4*)(W_ih + (size_t)(384 + j) * 64);
#pragma unroll 2
    for (int k4 = 0; k4 < 16; ++k4) {
        float4 wi = wip[k4], wf = wfp[k4], wg = wgp[k4], wo = wop[k4];
#pragma unroll
        for (int r = 0; r < 16; ++r) {
            float4 xv = *(const float4*)&xs[lr0 + r][4 * k4];
            ai[r] = dot4(xv, wi, ai[r]);
            af[r] = dot4(xv, wf, af[r]);
            ag[r] = dot4(xv, wg, ag[r]);
            ao[r] = dot4(xv, wo, ao[r]);
        }
    }
    // phase 2: K = 64..191 (recurrent, W_hh is (512,128) row-major)
    const float4* vip = (const float4*)(W_hh + (size_t)j * 128);
    const float4* vfp = (const float4*)(W_hh + (size_t)(128 + j) * 128);
    const float4* vgp = (const float4*)(W_hh + (size_t)(256 + j) * 128);
    const float4* vop = (const float4*)(W_hh + (size_t)(384 + j) * 128);
#pragma unroll 2
    for (int k4 = 0; k4 < 32; ++k4) {
        float4 wi = vip[k4], wf = vfp[k4], wg = vgp[k4], wo = vop[k4];
#pragma unroll
        for (int r = 0; r < 16; ++r) {
            float4 xv = *(const float4*)&xs[lr0 + r][64 + 4 * k4];
            ai[r] = dot4(xv, wi, ai[r]);
            af[r] = dot4(xv, wf, af[r]);
            ag[r] = dot4(xv, wg, ag[r]);
            ao[r] = dot4(xv, wo, ao[r]);
        }
    }
    // gating epilogue (in-place: this block owns these rows exclusively)
#pragma unroll
    for (int r = 0; r < 16; ++r) {
        int row = row0 + lr0 + r;
        if (row < N) {
            size_t off = (size_t)row * 128 + j;
            float cold = cbuf[off];
            float iv = sigf(ai[r]);
            float fv = sigf(af[r]);
            float gv = tanhfast(ag[r]);
            float ov = sigf(ao[r]);
            float cnew = fmaf(fv, cold, iv * gv);
            float hnew = ov * tanhfast(cnew);
            cbuf[off] = cnew;
            hbuf[off] = hnew;
        }
    }
}

// ---------------- MLP head: out = relu(h @ Wf1 + bf1) @ Wf2 + bf2 ----------------
// wave per node; lane = (half, j): halves split K=128, j indexes the 32 hidden units.
__global__ __launch_bounds__(256) void k_mlp(const float* __restrict__ hbuf, const float* __restrict__ Wf1,
                                             const float* __restrict__ bf1, const float* __restrict__ Wf2,
                                             const float* __restrict__ bf2, float* __restrict__ out, int N) {
    int lane = threadIdx.x & 63;
    int v = blockIdx.x * 4 + (threadIdx.x >> 6);
    if (v >= N) return;
    int j = lane & 31;
    int half = lane >> 5;
    const float* hr = hbuf + (size_t)v * 128 + half * 64;
    float s = 0.f;
#pragma unroll
    for (int k = 0; k < 64; ++k) s = fmaf(hr[k], Wf1[(half * 64 + k) * 32 + j], s);
    s += __shfl_down(s, 32, 64);
    float z = fmaxf(s + bf1[j], 0.f);
    float p = z * Wf2[j];
#pragma unroll
    for (int off = 16; off > 0; off >>= 1) p += __shfl_down(p, off, 64);
    if (lane == 0) out[v] = p + bf2[0];
}

extern "C" void kernel_launch(void* const* d_in, const int* in_sizes, int n_in,
                              void* d_out, int out_size, void* d_ws, size_t ws_size,
                              hipStream_t stream) {
    const float* x_seq = (const float*)d_in[0];
    const int* eidx = (const int*)d_in[1];
    const float* W1 = (const float*)d_in[2];
    const float* b1 = (const float*)d_in[3];
    const float* W2 = (const float*)d_in[4];
    const float* b2 = (const float*)d_in[5];
    const float* W_ih = (const float*)d_in[6];
    const float* W_hh = (const float*)d_in[7];
    const float* b_ih = (const float*)d_in[8];
    const float* b_hh = (const float*)d_in[9];
    const float* Wf1 = (const float*)d_in[10];
    const float* bf1 = (const float*)d_in[11];
    const float* Wf2 = (const float*)d_in[12];
    const float* bf2 = (const float*)d_in[13];

    int N = out_size;                 // 50000
    int E = in_sizes[1] / 2;          // 1,600,000
    int T = in_sizes[0] / (N * 16);   // 24
    const int* srcp = eidx;
    const int* dstp = eidx + E;

    // workspace carve-out (~84 MB total)
    char* ws = (char*)d_ws;
    size_t off = 0;
    auto alloc = [&](size_t bytes) -> char* {
        char* p = ws + off;
        off = (off + bytes + 255) & ~(size_t)255;
        return p;
    };
    int* deg = (int*)alloc((size_t)N * 4);
    int* row_ptr = (int*)alloc(((size_t)N + 1) * 4);
    int* cursor = (int*)alloc((size_t)N * 4);
    int* col = (int*)alloc((size_t)E * 4);
    float* dinv = (float*)alloc((size_t)N * 4);
    float* bufA = (float*)alloc((size_t)N * 64 * 4);
    float* bufB = (float*)alloc((size_t)N * 64 * 4);
    float* hbuf = (float*)alloc((size_t)N * 128 * 4);
    float* cbuf = (float*)alloc((size_t)N * 128 * 4);

    hipMemsetAsync(deg, 0, (size_t)N * 4, stream);
    hipMemsetAsync(hbuf, 0, (size_t)N * 128 * 4, stream);
    hipMemsetAsync(cbuf, 0, (size_t)N * 128 * 4, stream);

    k_count<<<(E + 255) / 256, 256, 0, stream>>>(dstp, E, deg);
    k_dinv<<<(N + 255) / 256, 256, 0, stream>>>(deg, dinv, N);
    k_scan<<<1, 1024, 0, stream>>>(deg, row_ptr, cursor, N);
    k_fill<<<(E + 255) / 256, 256, 0, stream>>>(srcp, dstp, E, cursor, col);

    int gemm_blocks = (N + 15) / 16;
    int agg_blocks = (N + 3) / 4;
    int lstm_blocks = (N + RB - 1) / RB;
    for (int t = 0; t < T; ++t) {
        const float* xt = x_seq + (size_t)t * N * 16;
        k_gemm_xW1<<<gemm_blocks, 256, 0, stream>>>(xt, W1, dinv, bufA, N);
        k_agg<<<agg_blocks, 256, 0, stream>>>(bufA, dinv, row_ptr, col, b1, bufB, N);
        k_gemm_hW2<<<gemm_blocks, 256, 0, stream>>>(bufB, W2, dinv, bufA, N);
        k_agg<<<agg_blocks, 256, 0, stream>>>(bufA, dinv, row_ptr, col, b2, bufB, N);
        k_lstm<<<lstm_blocks, 512, 0, stream>>>(bufB, hbuf, cbuf, W_ih, W_hh, b_ih, b_hh, N);
    }
    k_mlp<<<agg_blocks, 256, 0, stream>>>(hbuf, Wf1, bf1, Wf2, bf2, (float*)d_out, N);
}

// Round 2
// 7816.805 us; speedup vs baseline: 1.4161x; 1.4161x over previous
//
#include <hip/hip_runtime.h>
#include <hip/hip_bf16.h>
#include <math.h>

// SpatialTemporalModel: GCN(2-layer, symmetric-norm w/ self loops) x24 steps
// -> LSTM(LH=128) -> MLP head.
// Round 2: LSTM GEMM moved to bf16x3 MFMA (v_mfma_f32_32x32x16_bf16),
// ~fp32 precision via hi/lo split. GCN path unchanged.

#define RB 64  // rows per LSTM block

typedef short s16x8 __attribute__((ext_vector_type(8)));
typedef float f32x16 __attribute__((ext_vector_type(16)));
typedef unsigned long long u64;
union AF { s16x8 v; u64 q[2]; };

__device__ __forceinline__ float sigf(float x) { return 1.f / (1.f + __expf(-x)); }
__device__ __forceinline__ float tanhfast(float x) { return 1.f - 2.f / (1.f + __expf(2.f * x)); }
__device__ __forceinline__ float dot4(float4 a, float4 b, float acc) {
    return fmaf(a.x, b.x, fmaf(a.y, b.y, fmaf(a.z, b.z, fmaf(a.w, b.w, acc))));
}

// round-to-nearest-even f32 -> bf16 bits
__device__ __forceinline__ unsigned bfr(float x) {
    union { float f; unsigned u; } c; c.f = x;
    return (c.u + 0x7fffu + ((c.u >> 16) & 1u)) >> 16;
}
__device__ __forceinline__ void bsplit(float x, unsigned short& hi, unsigned short& lo) {
    unsigned h = bfr(x);
    union { unsigned u; float f; } hf; hf.u = h << 16;
    hi = (unsigned short)h;
    lo = (unsigned short)bfr(x - hf.f);
}

// ---------------- CSR build ----------------
__global__ void k_count(const int* __restrict__ dst, int E, int* __restrict__ deg) {
    int e = blockIdx.x * blockDim.x + threadIdx.x;
    if (e < E) atomicAdd(&deg[dst[e]], 1);
}

__global__ void k_dinv(const int* __restrict__ deg, float* __restrict__ dinv, int N) {
    int v = blockIdx.x * blockDim.x + threadIdx.x;
    if (v < N) dinv[v] = rsqrtf((float)deg[v] + 1.0f);
}

__global__ __launch_bounds__(1024) void k_scan(const int* __restrict__ deg, int* __restrict__ row_ptr,
                                               int* __restrict__ cursor, int N) {
    __shared__ int part[1024];
    int tid = threadIdx.x;
    int C = (N + 1023) >> 10;
    int s0 = tid * C;
    int s1 = min(s0 + C, N);
    int s = 0;
    for (int i = s0; i < s1; ++i) s += deg[i];
    part[tid] = s;
    __syncthreads();
    for (int off = 1; off < 1024; off <<= 1) {
        int v = (tid >= off) ? part[tid - off] : 0;
        __syncthreads();
        part[tid] += v;
        __syncthreads();
    }
    int base = (tid == 0) ? 0 : part[tid - 1];
    for (int i = s0; i < s1; ++i) {
        row_ptr[i] = base;
        cursor[i] = base;
        base += deg[i];
    }
    if (tid == 1023) row_ptr[N] = base;
}

__global__ void k_fill(const int* __restrict__ src, const int* __restrict__ dst, int E,
                       int* __restrict__ cursor, int* __restrict__ col) {
    int e = blockIdx.x * blockDim.x + threadIdx.x;
    if (e < E) {
        int d = dst[e];
        int p = atomicAdd(&cursor[d], 1);
        col[p] = src[e];
    }
}

// ---------------- LSTM weight prep: Wcat (512,192) split into bf16 hi/lo ----------------
__global__ void k_wprep(const float* __restrict__ W_ih, const float* __restrict__ W_hh,
                        unsigned short* __restrict__ whi, unsigned short* __restrict__ wlo) {
    int i = blockIdx.x * 256 + threadIdx.x;
    if (i >= 512 * 192) return;
    int g = i / 192, k = i - g * 192;
    float wv = (k < 64) ? W_ih[g * 64 + k] : W_hh[g * 128 + (k - 64)];
    unsigned short h, l;
    bsplit(wv, h, l);
    whi[i] = h;
    wlo[i] = l;
}

// ---------------- GCN: x_t @ W1, pre-scaled by dinv ----------------
__global__ __launch_bounds__(256) void k_gemm_xW1(const float* __restrict__ x, const float* __restrict__ W1,
                                                  const float* __restrict__ dinv, float* __restrict__ out, int N) {
    __shared__ float w[16 * 64];
    int tid = threadIdx.x;
    ((float4*)w)[tid] = ((const float4*)W1)[tid];
    __syncthreads();
    int h = tid & 63;
    int rg = __builtin_amdgcn_readfirstlane(tid >> 6);
    int v0 = blockIdx.x * 16 + rg * 4;
    float acc[4] = {0.f, 0.f, 0.f, 0.f};
#pragma unroll
    for (int r = 0; r < 4; ++r) {
        if (v0 + r < N) {
            const float4* xr = (const float4*)(x + (size_t)(v0 + r) * 16);
            float4 xa = xr[0], xb = xr[1], xc = xr[2], xd = xr[3];
            float a = acc[r];
            a = fmaf(xa.x, w[0 * 64 + h], a);  a = fmaf(xa.y, w[1 * 64 + h], a);
            a = fmaf(xa.z, w[2 * 64 + h], a);  a = fmaf(xa.w, w[3 * 64 + h], a);
            a = fmaf(xb.x, w[4 * 64 + h], a);  a = fmaf(xb.y, w[5 * 64 + h], a);
            a = fmaf(xb.z, w[6 * 64 + h], a);  a = fmaf(xb.w, w[7 * 64 + h], a);
            a = fmaf(xc.x, w[8 * 64 + h], a);  a = fmaf(xc.y, w[9 * 64 + h], a);
            a = fmaf(xc.z, w[10 * 64 + h], a); a = fmaf(xc.w, w[11 * 64 + h], a);
            a = fmaf(xd.x, w[12 * 64 + h], a); a = fmaf(xd.y, w[13 * 64 + h], a);
            a = fmaf(xd.z, w[14 * 64 + h], a); a = fmaf(xd.w, w[15 * 64 + h], a);
            acc[r] = a;
        }
    }
#pragma unroll
    for (int r = 0; r < 4; ++r)
        if (v0 + r < N) out[(size_t)(v0 + r) * 64 + h] = acc[r] * dinv[v0 + r];
}

// ---------------- GCN: h1 @ W2, pre-scaled by dinv ----------------
__global__ __launch_bounds__(256) void k_gemm_hW2(const float* __restrict__ hin, const float* __restrict__ W2,
                                                  const float* __restrict__ dinv, float* __restrict__ out, int N) {
    __shared__ float w[64 * 64];
    int tid = threadIdx.x;
#pragma unroll
    for (int i = 0; i < 4; ++i) ((float4*)w)[tid + 256 * i] = ((const float4*)W2)[tid + 256 * i];
    __syncthreads();
    int h = tid & 63;
    int rg = __builtin_amdgcn_readfirstlane(tid >> 6);
    int v0 = blockIdx.x * 16 + rg * 4;
    float acc[4] = {0.f, 0.f, 0.f, 0.f};
#pragma unroll 4
    for (int k4 = 0; k4 < 16; ++k4) {
        float w0 = w[(4 * k4 + 0) * 64 + h];
        float w1 = w[(4 * k4 + 1) * 64 + h];
        float w2v = w[(4 * k4 + 2) * 64 + h];
        float w3 = w[(4 * k4 + 3) * 64 + h];
#pragma unroll
        for (int r = 0; r < 4; ++r) {
            if (v0 + r < N) {
                float4 xv = *(const float4*)(hin + (size_t)(v0 + r) * 64 + 4 * k4);
                float a = acc[r];
                a = fmaf(xv.x, w0, a);
                a = fmaf(xv.y, w1, a);
                a = fmaf(xv.z, w2v, a);
                a = fmaf(xv.w, w3, a);
                acc[r] = a;
            }
        }
    }
#pragma unroll
    for (int r = 0; r < 4; ++r)
        if (v0 + r < N) out[(size_t)(v0 + r) * 64 + h] = acc[r] * dinv[v0 + r];
}

// ---------------- aggregation: relu(dinv[v]*(self + csr_sum) + bias) ----------------
__global__ __launch_bounds__(256) void k_agg(const float* __restrict__ tin, const float* __restrict__ dinv,
                                             const int* __restrict__ row_ptr, const int* __restrict__ col,
                                             const float* __restrict__ bias, float* __restrict__ out, int N) {
    int lane = threadIdx.x & 63;
    int v = blockIdx.x * 4 + (threadIdx.x >> 6);
    v = __builtin_amdgcn_readfirstlane(v);
    if (v >= N) return;
    float s = tin[(size_t)v * 64 + lane];
    int b = row_ptr[v];
    int e = row_ptr[v + 1];
    for (int i = b; i < e; ++i) {
        int c = col[i];
        s += tin[(size_t)c * 64 + lane];
    }
    float r = fmaf(dinv[v], s, bias[lane]);
    out[(size_t)v * 64 + lane] = fmaxf(r, 0.f);
}

// ---------------- fused LSTM step via bf16x3 MFMA ----------------
// block 256 = 4 waves, 64 rows/block. Wave w owns cols [32w,32w+32) of ALL 4 gates
// -> gating is wave-local. K=192 in 12 chunks of 16. A (x|h) split hi/lo into LDS
// (row stride 392 B: 2-way bank alias = free, 8B aligned). B streamed from the
// pre-split bf16 weight table (L2-resident), reused across both 32-row subtiles.
__global__ __launch_bounds__(256, 2) void k_lstm_mfma(const float* __restrict__ xin,
                                                      float* __restrict__ hbuf, float* __restrict__ cbuf,
                                                      const unsigned short* __restrict__ whi,
                                                      const unsigned short* __restrict__ wlo,
                                                      const float* __restrict__ b_ih, const float* __restrict__ b_hh,
                                                      int N) {
    // 64 rows x 392 bytes, hi and lo parts
    __shared__ __align__(16) char lds_hi[64 * 392];
    __shared__ __align__(16) char lds_lo[64 * 392];
    int tid = threadIdx.x;
    int row0 = blockIdx.x * RB;

    // ---- stage A = [x(64) | h(128)] as bf16 hi/lo, MFMA-group-packed rows ----
    // idx enumerates (m, c) with c in [0,48) float4-chunks of the 192-wide row
    int idx = tid;
#pragma unroll
    for (int it = 0; it < 12; ++it, idx += 256) {
        int m = idx / 48;
        int c = idx - m * 48;
        int row = row0 + m;
        float4 v = make_float4(0.f, 0.f, 0.f, 0.f);
        if (row < N)
            v = (c < 16) ? ((const float4*)xin)[(size_t)row * 16 + c]
                         : ((const float4*)hbuf)[(size_t)row * 32 + (c - 16)];
        unsigned short h0, h1, h2, h3, l0, l1, l2, l3;
        bsplit(v.x, h0, l0); bsplit(v.y, h1, l1); bsplit(v.z, h2, l2); bsplit(v.w, h3, l3);
        u64 hq = (u64)h0 | ((u64)h1 << 16) | ((u64)h2 << 32) | ((u64)h3 << 48);
        u64 lq = (u64)l0 | ((u64)l1 << 16) | ((u64)l2 << 32) | ((u64)l3 << 48);
        size_t boff = (size_t)m * 392 + (size_t)(c >> 1) * 16 + (size_t)(c & 1) * 8;
        *(u64*)(lds_hi + boff) = hq;
        *(u64*)(lds_lo + boff) = lq;
    }
    __syncthreads();

    int lane = tid & 63;
    int w = tid >> 6;       // wave id = col group
    int l31 = lane & 31;
    int hf = lane >> 5;     // K-half within chunk
    int col = w * 32 + l31; // gate channel j in [0,128)

    f32x16 acc[2][4];
#pragma unroll
    for (int s = 0; s < 2; ++s)
#pragma unroll
        for (int g = 0; g < 4; ++g)
#pragma unroll
            for (int r = 0; r < 16; ++r) acc[s][g][r] = 0.f;

    const char* whc = (const char*)whi;
    const char* wlc = (const char*)wlo;
    size_t bbase[4];
#pragma unroll
    for (int g = 0; g < 4; ++g) bbase[g] = (size_t)(g * 128 + col) * 384 + (size_t)hf * 16;
    size_t abase0 = (size_t)l31 * 392 + (size_t)hf * 16;
    size_t abase1 = (size_t)(32 + l31) * 392 + (size_t)hf * 16;

#pragma unroll
    for (int kc = 0; kc < 12; ++kc) {
        AF ahi0, alo0, ahi1, alo1;
        size_t a0 = abase0 + (size_t)kc * 32;
        size_t a1 = abase1 + (size_t)kc * 32;
        ahi0.q[0] = *(const u64*)(lds_hi + a0); ahi0.q[1] = *(const u64*)(lds_hi + a0 + 8);
        alo0.q[0] = *(const u64*)(lds_lo + a0); alo0.q[1] = *(const u64*)(lds_lo + a0 + 8);
        ahi1.q[0] = *(const u64*)(lds_hi + a1); ahi1.q[1] = *(const u64*)(lds_hi + a1 + 8);
        alo1.q[0] = *(const u64*)(lds_lo + a1); alo1.q[1] = *(const u64*)(lds_lo + a1 + 8);
        AF bhi[4], blo[4];
#pragma unroll
        for (int g = 0; g < 4; ++g) {
            size_t bo = bbase[g] + (size_t)kc * 32;
            bhi[g].v = *(const s16x8*)(whc + bo);
            blo[g].v = *(const s16x8*)(wlc + bo);
        }
#pragma unroll
        for (int g = 0; g < 4; ++g) {
            acc[0][g] = __builtin_amdgcn_mfma_f32_32x32x16_bf16(ahi0.v, bhi[g].v, acc[0][g], 0, 0, 0);
            acc[0][g] = __builtin_amdgcn_mfma_f32_32x32x16_bf16(alo0.v, bhi[g].v, acc[0][g], 0, 0, 0);
            acc[0][g] = __builtin_amdgcn_mfma_f32_32x32x16_bf16(ahi0.v, blo[g].v, acc[0][g], 0, 0, 0);
            acc[1][g] = __builtin_amdgcn_mfma_f32_32x32x16_bf16(ahi1.v, bhi[g].v, acc[1][g], 0, 0, 0);
            acc[1][g] = __builtin_amdgcn_mfma_f32_32x32x16_bf16(alo1.v, bhi[g].v, acc[1][g], 0, 0, 0);
            acc[1][g] = __builtin_amdgcn_mfma_f32_32x32x16_bf16(ahi1.v, blo[g].v, acc[1][g], 0, 0, 0);
        }
    }

    // ---- gating epilogue: C/D layout col=lane&31, row=(r&3)+8*(r>>2)+4*(lane>>5) ----
    float bi = b_ih[col] + b_hh[col];
    float bff = b_ih[128 + col] + b_hh[128 + col];
    float bg = b_ih[256 + col] + b_hh[256 + col];
    float bo = b_ih[384 + col] + b_hh[384 + col];
#pragma unroll
    for (int s = 0; s < 2; ++s) {
#pragma unroll
        for (int r = 0; r < 16; ++r) {
            int rl = (r & 3) + 8 * (r >> 2) + 4 * hf;
            int row = row0 + s * 32 + rl;
            if (row < N) {
                size_t off = (size_t)row * 128 + col;
                float iv = sigf(acc[s][0][r] + bi);
                float fv = sigf(acc[s][1][r] + bff);
                float gv = tanhfast(acc[s][2][r] + bg);
                float ov = sigf(acc[s][3][r] + bo);
                float cnew = fmaf(fv, cbuf[off], iv * gv);
                float hnew = ov * tanhfast(cnew);
                cbuf[off] = cnew;
                hbuf[off] = hnew;
            }
        }
    }
}

// ---------------- MLP head: out = relu(h @ Wf1 + bf1) @ Wf2 + bf2 ----------------
__global__ __launch_bounds__(256) void k_mlp(const float* __restrict__ hbuf, const float* __restrict__ Wf1,
                                             const float* __restrict__ bf1, const float* __restrict__ Wf2,
                                             const float* __restrict__ bf2, float* __restrict__ out, int N) {
    int lane = threadIdx.x & 63;
    int v = blockIdx.x * 4 + (threadIdx.x >> 6);
    if (v >= N) return;
    int j = lane & 31;
    int half = lane >> 5;
    const float* hr = hbuf + (size_t)v * 128 + half * 64;
    float s = 0.f;
#pragma unroll
    for (int k = 0; k < 64; ++k) s = fmaf(hr[k], Wf1[(half * 64 + k) * 32 + j], s);
    s += __shfl_down(s, 32, 64);
    float z = fmaxf(s + bf1[j], 0.f);
    float p = z * Wf2[j];
#pragma unroll
    for (int off = 16; off > 0; off >>= 1) p += __shfl_down(p, off, 64);
    if (lane == 0) out[v] = p + bf2[0];
}

extern "C" void kernel_launch(void* const* d_in, const int* in_sizes, int n_in,
                              void* d_out, int out_size, void* d_ws, size_t ws_size,
                              hipStream_t stream) {
    const float* x_seq = (const float*)d_in[0];
    const int* eidx = (const int*)d_in[1];
    const float* W1 = (const float*)d_in[2];
    const float* b1 = (const float*)d_in[3];
    const float* W2 = (const float*)d_in[4];
    const float* b2 = (const float*)d_in[5];
    const float* W_ih = (const float*)d_in[6];
    const float* W_hh = (const float*)d_in[7];
    const float* b_ih = (const float*)d_in[8];
    const float* b_hh = (const float*)d_in[9];
    const float* Wf1 = (const float*)d_in[10];
    const float* bf1 = (const float*)d_in[11];
    const float* Wf2 = (const float*)d_in[12];
    const float* bf2 = (const float*)d_in[13];

    int N = out_size;                 // 50000
    int E = in_sizes[1] / 2;          // 1,600,000
    int T = in_sizes[0] / (N * 16);   // 24
    const int* srcp = eidx;
    const int* dstp = eidx + E;

    char* ws = (char*)d_ws;
    size_t off = 0;
    auto alloc = [&](size_t bytes) -> char* {
        char* p = ws + off;
        off = (off + bytes + 255) & ~(size_t)255;
        return p;
    };
    int* deg = (int*)alloc((size_t)N * 4);
    int* row_ptr = (int*)alloc(((size_t)N + 1) * 4);
    int* cursor = (int*)alloc((size_t)N * 4);
    int* col = (int*)alloc((size_t)E * 4);
    float* dinv = (float*)alloc((size_t)N * 4);
    float* bufA = (float*)alloc((size_t)N * 64 * 4);
    float* bufB = (float*)alloc((size_t)N * 64 * 4);
    float* hbuf = (float*)alloc((size_t)N * 128 * 4);
    float* cbuf = (float*)alloc((size_t)N * 128 * 4);
    unsigned short* whi = (unsigned short*)alloc((size_t)512 * 192 * 2);
    unsigned short* wlo = (unsigned short*)alloc((size_t)512 * 192 * 2);

    hipMemsetAsync(deg, 0, (size_t)N * 4, stream);
    hipMemsetAsync(hbuf, 0, (size_t)N * 128 * 4, stream);
    hipMemsetAsync(cbuf, 0, (size_t)N * 128 * 4, stream);

    k_count<<<(E + 255) / 256, 256, 0, stream>>>(dstp, E, deg);
    k_dinv<<<(N + 255) / 256, 256, 0, stream>>>(deg, dinv, N);
    k_scan<<<1, 1024, 0, stream>>>(deg, row_ptr, cursor, N);
    k_fill<<<(E + 255) / 256, 256, 0, stream>>>(srcp, dstp, E, cursor, col);
    k_wprep<<<(512 * 192 + 255) / 256, 256, 0, stream>>>(W_ih, W_hh, whi, wlo);

    int gemm_blocks = (N + 15) / 16;
    int agg_blocks = (N + 3) / 4;
    int lstm_blocks = (N + RB - 1) / RB;
    for (int t = 0; t < T; ++t) {
        const float* xt = x_seq + (size_t)t * N * 16;
        k_gemm_xW1<<<gemm_blocks, 256, 0, stream>>>(xt, W1, dinv, bufA, N);
        k_agg<<<agg_blocks, 256, 0, stream>>>(bufA, dinv, row_ptr, col, b1, bufB, N);
        k_gemm_hW2<<<gemm_blocks, 256, 0, stream>>>(bufB, W2, dinv, bufA, N);
        k_agg<<<agg_blocks, 256, 0, stream>>>(bufA, dinv, row_ptr, col, b2, bufB, N);
        k_lstm_mfma<<<lstm_blocks, 256, 0, stream>>>(bufB, hbuf, cbuf, whi, wlo, b_ih, b_hh, N);
    }
    k_mlp<<<agg_blocks, 256, 0, stream>>>(hbuf, Wf1, bf1, Wf2, bf2, (float*)d_out, N);
}

// Round 3
// 6175.799 us; speedup vs baseline: 1.7924x; 1.2657x over previous
//
#include <hip/hip_runtime.h>
#include <hip/hip_bf16.h>
#include <math.h>

// SpatialTemporalModel: GCN(2-layer) x24 -> LSTM(128) -> MLP head.
// Round 3: gather-before-GEMM on both GCN layers (agg is linear, so
// agg(x@W) == (agg x)@W): layer-1 gathers at width 16 (410->102 MB/step,
// table L2-resident), layer-2 gathers a bf16 table (410->205 MB/step).
// LSTM stays bf16x3 MFMA.

#define RB 64  // rows per LSTM block

typedef short s16x8 __attribute__((ext_vector_type(8)));
typedef float f32x16 __attribute__((ext_vector_type(16)));
typedef unsigned long long u64;
union AF { s16x8 v; u64 q[2]; };

__device__ __forceinline__ float sigf(float x) { return 1.f / (1.f + __expf(-x)); }
__device__ __forceinline__ float tanhfast(float x) { return 1.f - 2.f / (1.f + __expf(2.f * x)); }

// round-to-nearest-even f32 -> bf16 bits
__device__ __forceinline__ unsigned bfr(float x) {
    union { float f; unsigned u; } c; c.f = x;
    return (c.u + 0x7fffu + ((c.u >> 16) & 1u)) >> 16;
}
__device__ __forceinline__ void bsplit(float x, unsigned short& hi, unsigned short& lo) {
    unsigned h = bfr(x);
    union { unsigned u; float f; } hf; hf.u = h << 16;
    hi = (unsigned short)h;
    lo = (unsigned short)bfr(x - hf.f);
}
__device__ __forceinline__ float bf2f(unsigned short b) {
    union { unsigned u; float f; } c; c.u = ((unsigned)b) << 16;
    return c.f;
}

// ---------------- CSR build ----------------
__global__ void k_count(const int* __restrict__ dst, int E, int* __restrict__ deg) {
    int e = blockIdx.x * blockDim.x + threadIdx.x;
    if (e < E) atomicAdd(&deg[dst[e]], 1);
}

__global__ void k_dinv(const int* __restrict__ deg, float* __restrict__ dinv, int N) {
    int v = blockIdx.x * blockDim.x + threadIdx.x;
    if (v < N) dinv[v] = rsqrtf((float)deg[v] + 1.0f);
}

__global__ __launch_bounds__(1024) void k_scan(const int* __restrict__ deg, int* __restrict__ row_ptr,
                                               int* __restrict__ cursor, int N) {
    __shared__ int part[1024];
    int tid = threadIdx.x;
    int C = (N + 1023) >> 10;
    int s0 = tid * C;
    int s1 = min(s0 + C, N);
    int s = 0;
    for (int i = s0; i < s1; ++i) s += deg[i];
    part[tid] = s;
    __syncthreads();
    for (int off = 1; off < 1024; off <<= 1) {
        int v = (tid >= off) ? part[tid - off] : 0;
        __syncthreads();
        part[tid] += v;
        __syncthreads();
    }
    int base = (tid == 0) ? 0 : part[tid - 1];
    for (int i = s0; i < s1; ++i) {
        row_ptr[i] = base;
        cursor[i] = base;
        base += deg[i];
    }
    if (tid == 1023) row_ptr[N] = base;
}

__global__ void k_fill(const int* __restrict__ src, const int* __restrict__ dst, int E,
                       int* __restrict__ cursor, int* __restrict__ col) {
    int e = blockIdx.x * blockDim.x + threadIdx.x;
    if (e < E) {
        int d = dst[e];
        int p = atomicAdd(&cursor[d], 1);
        col[p] = src[e];
    }
}

// ---------------- LSTM weight prep: Wcat (512,192) split into bf16 hi/lo ----------------
__global__ void k_wprep(const float* __restrict__ W_ih, const float* __restrict__ W_hh,
                        unsigned short* __restrict__ whi, unsigned short* __restrict__ wlo) {
    int i = blockIdx.x * 256 + threadIdx.x;
    if (i >= 512 * 192) return;
    int g = i / 192, k = i - g * 192;
    float wv = (k < 64) ? W_ih[g * 64 + k] : W_hh[g * 128 + (k - 64)];
    unsigned short h, l;
    bsplit(wv, h, l);
    whi[i] = h;
    wlo[i] = l;
}

// ---------------- layer-1 aggregation at width 16 ----------------
// u[v] = dinv[v] * ( sum_{src->v} dinv[src]*x[src,:] + dinv[v]*x[v,:] )   (N,16)
// wave per node; lanes = 4 groups x 16 channels; group g walks edges b+g, b+g+4, ...
__global__ __launch_bounds__(256) void k_agg16(const float* __restrict__ x, const float* __restrict__ dinv,
                                               const int* __restrict__ row_ptr, const int* __restrict__ col,
                                               float* __restrict__ u, int N) {
    int lane = threadIdx.x & 63;
    int v = blockIdx.x * 4 + (threadIdx.x >> 6);
    if (v >= N) return;
    int chan = lane & 15;
    int grp = lane >> 4;
    int b = row_ptr[v];
    int e = row_ptr[v + 1];
    float s = 0.f;
    for (int i = b + grp; i < e; i += 4) {
        int c = col[i];
        s = fmaf(dinv[c], x[(size_t)c * 16 + chan], s);
    }
    s += __shfl_xor(s, 16, 64);
    s += __shfl_xor(s, 32, 64);
    float dv = dinv[v];
    float tot = dv * fmaf(dv, x[(size_t)v * 16 + chan], s);
    if (lane < 16) u[(size_t)v * 16 + chan] = tot;
}

// ---------------- h1' = dinv * relu(u @ W1 + b1), stored bf16 ----------------
__global__ __launch_bounds__(256) void k_h1(const float* __restrict__ u, const float* __restrict__ W1,
                                            const float* __restrict__ b1, const float* __restrict__ dinv,
                                            unsigned short* __restrict__ h1bf, int N) {
    __shared__ float w[16 * 64];
    int tid = threadIdx.x;
    ((float4*)w)[tid] = ((const float4*)W1)[tid];
    __syncthreads();
    int h = tid & 63;
    int rg = __builtin_amdgcn_readfirstlane(tid >> 6);
    int v0 = blockIdx.x * 16 + rg * 4;
    float bv = b1[h];
#pragma unroll
    for (int r = 0; r < 4; ++r) {
        int v = v0 + r;
        if (v < N) {
            const float4* xr = (const float4*)(u + (size_t)v * 16);
            float4 xa = xr[0], xb = xr[1], xc = xr[2], xd = xr[3];
            float a = bv;
            a = fmaf(xa.x, w[0 * 64 + h], a);  a = fmaf(xa.y, w[1 * 64 + h], a);
            a = fmaf(xa.z, w[2 * 64 + h], a);  a = fmaf(xa.w, w[3 * 64 + h], a);
            a = fmaf(xb.x, w[4 * 64 + h], a);  a = fmaf(xb.y, w[5 * 64 + h], a);
            a = fmaf(xb.z, w[6 * 64 + h], a);  a = fmaf(xb.w, w[7 * 64 + h], a);
            a = fmaf(xc.x, w[8 * 64 + h], a);  a = fmaf(xc.y, w[9 * 64 + h], a);
            a = fmaf(xc.z, w[10 * 64 + h], a); a = fmaf(xc.w, w[11 * 64 + h], a);
            a = fmaf(xd.x, w[12 * 64 + h], a); a = fmaf(xd.y, w[13 * 64 + h], a);
            a = fmaf(xd.z, w[14 * 64 + h], a); a = fmaf(xd.w, w[15 * 64 + h], a);
            float r1 = fmaxf(a, 0.f) * dinv[v];
            h1bf[(size_t)v * 64 + h] = (unsigned short)bfr(r1);
        }
    }
}

// ---------------- layer-2 aggregation over bf16 table ----------------
// vout[v] = dinv[v] * ( sum_{src->v} h1'[src,:] + h1'[v,:] )   (N,64) fp32
// wave per node; lane = (half, chanpair): 32 uint lanes cover 64 bf16 channels,
// halves split the edge list 2-way.
__global__ __launch_bounds__(256) void k_agg64bf(const unsigned short* __restrict__ h1bf,
                                                 const float* __restrict__ dinv,
                                                 const int* __restrict__ row_ptr, const int* __restrict__ col,
                                                 float* __restrict__ vout, int N) {
    int lane = threadIdx.x & 63;
    int v = blockIdx.x * 4 + (threadIdx.x >> 6);
    if (v >= N) return;
    int cp = lane & 31;
    int half = lane >> 5;
    int b = row_ptr[v];
    int e = row_ptr[v + 1];
    float s0 = 0.f, s1 = 0.f;
    const unsigned* tbl = (const unsigned*)h1bf;
    for (int i = b + half; i < e; i += 2) {
        int c = col[i];
        unsigned w = tbl[(size_t)c * 32 + cp];
        s0 += bf2f((unsigned short)(w & 0xffffu));
        s1 += bf2f((unsigned short)(w >> 16));
    }
    s0 += __shfl_xor(s0, 32, 64);
    s1 += __shfl_xor(s1, 32, 64);
    if (half == 0) {
        unsigned sw = tbl[(size_t)v * 32 + cp];
        float dv = dinv[v];
        float t0 = dv * (s0 + bf2f((unsigned short)(sw & 0xffffu)));
        float t1 = dv * (s1 + bf2f((unsigned short)(sw >> 16)));
        ((float2*)(vout + (size_t)v * 64))[cp] = make_float2(t0, t1);
    }
}

// ---------------- h2 = relu(vout @ W2 + b2) ----------------
__global__ __launch_bounds__(256) void k_gemm_h2(const float* __restrict__ hin, const float* __restrict__ W2,
                                                 const float* __restrict__ b2, float* __restrict__ out, int N) {
    __shared__ float w[64 * 64];
    int tid = threadIdx.x;
#pragma unroll
    for (int i = 0; i < 4; ++i) ((float4*)w)[tid + 256 * i] = ((const float4*)W2)[tid + 256 * i];
    __syncthreads();
    int h = tid & 63;
    int rg = __builtin_amdgcn_readfirstlane(tid >> 6);
    int v0 = blockIdx.x * 16 + rg * 4;
    float bv = b2[h];
    float acc[4] = {bv, bv, bv, bv};
#pragma unroll 4
    for (int k4 = 0; k4 < 16; ++k4) {
        float w0 = w[(4 * k4 + 0) * 64 + h];
        float w1 = w[(4 * k4 + 1) * 64 + h];
        float w2v = w[(4 * k4 + 2) * 64 + h];
        float w3 = w[(4 * k4 + 3) * 64 + h];
#pragma unroll
        for (int r = 0; r < 4; ++r) {
            if (v0 + r < N) {
                float4 xv = *(const float4*)(hin + (size_t)(v0 + r) * 64 + 4 * k4);
                float a = acc[r];
                a = fmaf(xv.x, w0, a);
                a = fmaf(xv.y, w1, a);
                a = fmaf(xv.z, w2v, a);
                a = fmaf(xv.w, w3, a);
                acc[r] = a;
            }
        }
    }
#pragma unroll
    for (int r = 0; r < 4; ++r)
        if (v0 + r < N) out[(size_t)(v0 + r) * 64 + h] = fmaxf(acc[r], 0.f);
}

// ---------------- fused LSTM step via bf16x3 MFMA ----------------
__global__ __launch_bounds__(256, 2) void k_lstm_mfma(const float* __restrict__ xin,
                                                      float* __restrict__ hbuf, float* __restrict__ cbuf,
                                                      const unsigned short* __restrict__ whi,
                                                      const unsigned short* __restrict__ wlo,
                                                      const float* __restrict__ b_ih, const float* __restrict__ b_hh,
                                                      int N) {
    __shared__ __align__(16) char lds_hi[64 * 392];
    __shared__ __align__(16) char lds_lo[64 * 392];
    int tid = threadIdx.x;
    int row0 = blockIdx.x * RB;

    int idx = tid;
#pragma unroll
    for (int it = 0; it < 12; ++it, idx += 256) {
        int m = idx / 48;
        int c = idx - m * 48;
        int row = row0 + m;
        float4 v = make_float4(0.f, 0.f, 0.f, 0.f);
        if (row < N)
            v = (c < 16) ? ((const float4*)xin)[(size_t)row * 16 + c]
                         : ((const float4*)hbuf)[(size_t)row * 32 + (c - 16)];
        unsigned short h0, h1, h2, h3, l0, l1, l2, l3;
        bsplit(v.x, h0, l0); bsplit(v.y, h1, l1); bsplit(v.z, h2, l2); bsplit(v.w, h3, l3);
        u64 hq = (u64)h0 | ((u64)h1 << 16) | ((u64)h2 << 32) | ((u64)h3 << 48);
        u64 lq = (u64)l0 | ((u64)l1 << 16) | ((u64)l2 << 32) | ((u64)l3 << 48);
        size_t boff = (size_t)m * 392 + (size_t)(c >> 1) * 16 + (size_t)(c & 1) * 8;
        *(u64*)(lds_hi + boff) = hq;
        *(u64*)(lds_lo + boff) = lq;
    }
    __syncthreads();

    int lane = tid & 63;
    int w = tid >> 6;
    int l31 = lane & 31;
    int hf = lane >> 5;
    int col = w * 32 + l31;

    f32x16 acc[2][4];
#pragma unroll
    for (int s = 0; s < 2; ++s)
#pragma unroll
        for (int g = 0; g < 4; ++g)
#pragma unroll
            for (int r = 0; r < 16; ++r) acc[s][g][r] = 0.f;

    const char* whc = (const char*)whi;
    const char* wlc = (const char*)wlo;
    size_t bbase[4];
#pragma unroll
    for (int g = 0; g < 4; ++g) bbase[g] = (size_t)(g * 128 + col) * 384 + (size_t)hf * 16;
    size_t abase0 = (size_t)l31 * 392 + (size_t)hf * 16;
    size_t abase1 = (size_t)(32 + l31) * 392 + (size_t)hf * 16;

#pragma unroll
    for (int kc = 0; kc < 12; ++kc) {
        AF ahi0, alo0, ahi1, alo1;
        size_t a0 = abase0 + (size_t)kc * 32;
        size_t a1 = abase1 + (size_t)kc * 32;
        ahi0.q[0] = *(const u64*)(lds_hi + a0); ahi0.q[1] = *(const u64*)(lds_hi + a0 + 8);
        alo0.q[0] = *(const u64*)(lds_lo + a0); alo0.q[1] = *(const u64*)(lds_lo + a0 + 8);
        ahi1.q[0] = *(const u64*)(lds_hi + a1); ahi1.q[1] = *(const u64*)(lds_hi + a1 + 8);
        alo1.q[0] = *(const u64*)(lds_lo + a1); alo1.q[1] = *(const u64*)(lds_lo + a1 + 8);
        AF bhi[4], blo[4];
#pragma unroll
        for (int g = 0; g < 4; ++g) {
            size_t bo = bbase[g] + (size_t)kc * 32;
            bhi[g].v = *(const s16x8*)(whc + bo);
            blo[g].v = *(const s16x8*)(wlc + bo);
        }
#pragma unroll
        for (int g = 0; g < 4; ++g) {
            acc[0][g] = __builtin_amdgcn_mfma_f32_32x32x16_bf16(ahi0.v, bhi[g].v, acc[0][g], 0, 0, 0);
            acc[0][g] = __builtin_amdgcn_mfma_f32_32x32x16_bf16(alo0.v, bhi[g].v, acc[0][g], 0, 0, 0);
            acc[0][g] = __builtin_amdgcn_mfma_f32_32x32x16_bf16(ahi0.v, blo[g].v, acc[0][g], 0, 0, 0);
            acc[1][g] = __builtin_amdgcn_mfma_f32_32x32x16_bf16(ahi1.v, bhi[g].v, acc[1][g], 0, 0, 0);
            acc[1][g] = __builtin_amdgcn_mfma_f32_32x32x16_bf16(alo1.v, bhi[g].v, acc[1][g], 0, 0, 0);
            acc[1][g] = __builtin_amdgcn_mfma_f32_32x32x16_bf16(ahi1.v, blo[g].v, acc[1][g], 0, 0, 0);
        }
    }

    float bi = b_ih[col] + b_hh[col];
    float bff = b_ih[128 + col] + b_hh[128 + col];
    float bg = b_ih[256 + col] + b_hh[256 + col];
    float bo = b_ih[384 + col] + b_hh[384 + col];
#pragma unroll
    for (int s = 0; s < 2; ++s) {
#pragma unroll
        for (int r = 0; r < 16; ++r) {
            int rl = (r & 3) + 8 * (r >> 2) + 4 * hf;
            int row = row0 + s * 32 + rl;
            if (row < N) {
                size_t off = (size_t)row * 128 + col;
                float iv = sigf(acc[s][0][r] + bi);
                float fv = sigf(acc[s][1][r] + bff);
                float gv = tanhfast(acc[s][2][r] + bg);
                float ov = sigf(acc[s][3][r] + bo);
                float cnew = fmaf(fv, cbuf[off], iv * gv);
                float hnew = ov * tanhfast(cnew);
                cbuf[off] = cnew;
                hbuf[off] = hnew;
            }
        }
    }
}

// ---------------- MLP head ----------------
__global__ __launch_bounds__(256) void k_mlp(const float* __restrict__ hbuf, const float* __restrict__ Wf1,
                                             const float* __restrict__ bf1, const float* __restrict__ Wf2,
                                             const float* __restrict__ bf2, float* __restrict__ out, int N) {
    int lane = threadIdx.x & 63;
    int v = blockIdx.x * 4 + (threadIdx.x >> 6);
    if (v >= N) return;
    int j = lane & 31;
    int half = lane >> 5;
    const float* hr = hbuf + (size_t)v * 128 + half * 64;
    float s = 0.f;
#pragma unroll
    for (int k = 0; k < 64; ++k) s = fmaf(hr[k], Wf1[(half * 64 + k) * 32 + j], s);
    s += __shfl_down(s, 32, 64);
    float z = fmaxf(s + bf1[j], 0.f);
    float p = z * Wf2[j];
#pragma unroll
    for (int off = 16; off > 0; off >>= 1) p += __shfl_down(p, off, 64);
    if (lane == 0) out[v] = p + bf2[0];
}

extern "C" void kernel_launch(void* const* d_in, const int* in_sizes, int n_in,
                              void* d_out, int out_size, void* d_ws, size_t ws_size,
                              hipStream_t stream) {
    const float* x_seq = (const float*)d_in[0];
    const int* eidx = (const int*)d_in[1];
    const float* W1 = (const float*)d_in[2];
    const float* b1 = (const float*)d_in[3];
    const float* W2 = (const float*)d_in[4];
    const float* b2 = (const float*)d_in[5];
    const float* W_ih = (const float*)d_in[6];
    const float* W_hh = (const float*)d_in[7];
    const float* b_ih = (const float*)d_in[8];
    const float* b_hh = (const float*)d_in[9];
    const float* Wf1 = (const float*)d_in[10];
    const float* bf1 = (const float*)d_in[11];
    const float* Wf2 = (const float*)d_in[12];
    const float* bf2 = (const float*)d_in[13];

    int N = out_size;                 // 50000
    int E = in_sizes[1] / 2;          // 1,600,000
    int T = in_sizes[0] / (N * 16);   // 24
    const int* srcp = eidx;
    const int* dstp = eidx + E;

    char* ws = (char*)d_ws;
    size_t off = 0;
    auto alloc = [&](size_t bytes) -> char* {
        char* p = ws + off;
        off = (off + bytes + 255) & ~(size_t)255;
        return p;
    };
    int* deg = (int*)alloc((size_t)N * 4);
    int* row_ptr = (int*)alloc(((size_t)N + 1) * 4);
    int* cursor = (int*)alloc((size_t)N * 4);
    int* col = (int*)alloc((size_t)E * 4);
    float* dinv = (float*)alloc((size_t)N * 4);
    // region R: u (N x 16 f32, first 3.2 MB) aliases vbuf (N x 64 f32) —
    // lifetimes strictly sequenced: agg16->u, h1 reads u; agg64 writes vbuf.
    float* vbuf = (float*)alloc((size_t)N * 64 * 4);
    float* ubuf = vbuf;
    // region bufB: h1bf (N x 64 bf16, first 6.4 MB) aliases h2 (N x 64 f32) —
    // h1bf dead before k_gemm_h2 writes h2; h2 dead before next step's k_h1.
    float* bufB = (float*)alloc((size_t)N * 64 * 4);
    unsigned short* h1bf = (unsigned short*)bufB;
    float* hbuf = (float*)alloc((size_t)N * 128 * 4);
    float* cbuf = (float*)alloc((size_t)N * 128 * 4);
    unsigned short* whi = (unsigned short*)alloc((size_t)512 * 192 * 2);
    unsigned short* wlo = (unsigned short*)alloc((size_t)512 * 192 * 2);

    hipMemsetAsync(deg, 0, (size_t)N * 4, stream);
    hipMemsetAsync(hbuf, 0, (size_t)N * 128 * 4, stream);
    hipMemsetAsync(cbuf, 0, (size_t)N * 128 * 4, stream);

    k_count<<<(E + 255) / 256, 256, 0, stream>>>(dstp, E, deg);
    k_dinv<<<(N + 255) / 256, 256, 0, stream>>>(deg, dinv, N);
    k_scan<<<1, 1024, 0, stream>>>(deg, row_ptr, cursor, N);
    k_fill<<<(E + 255) / 256, 256, 0, stream>>>(srcp, dstp, E, cursor, col);
    k_wprep<<<(512 * 192 + 255) / 256, 256, 0, stream>>>(W_ih, W_hh, whi, wlo);

    int node_wave_blocks = (N + 3) / 4;   // 4 waves/block, wave per node
    int gemm_blocks = (N + 15) / 16;
    int lstm_blocks = (N + RB - 1) / RB;
    for (int t = 0; t < T; ++t) {
        const float* xt = x_seq + (size_t)t * N * 16;
        k_agg16<<<node_wave_blocks, 256, 0, stream>>>(xt, dinv, row_ptr, col, ubuf, N);
        k_h1<<<gemm_blocks, 256, 0, stream>>>(ubuf, W1, b1, dinv, h1bf, N);
        k_agg64bf<<<node_wave_blocks, 256, 0, stream>>>(h1bf, dinv, row_ptr, col, vbuf, N);
        k_gemm_h2<<<gemm_blocks, 256, 0, stream>>>(vbuf, W2, b2, bufB, N);
        k_lstm_mfma<<<lstm_blocks, 256, 0, stream>>>(bufB, hbuf, cbuf, whi, wlo, b_ih, b_hh, N);
    }
    k_mlp<<<node_wave_blocks, 256, 0, stream>>>(hbuf, Wf1, bf1, Wf2, bf2, (float*)d_out, N);
}